// Round 5
// baseline (134.922 us; speedup 1.0000x reference)
//
#include <hip/hip_runtime.h>
#include <hip/hip_cooperative_groups.h>
#include <math.h>

namespace cg = cooperative_groups;

#define HW2   196      // 14*14
#define IMG   224
#define IMG2  (224*224)
#define MAXBLK 4096

// One fused cooperative kernel.
// Phase 1: grid-stride over groups of 4 patches; one wave (64 lanes) per patch.
//          Lane = row*4 + c4, each lane loads float4 (64B/row/wave segments).
//          Per-block {min,max,sum} partials -> ws.
// grid.sync()
// Phase 2: first nchunks blocks redundantly reduce the partials (L2-resident,
//          fixed order -> deterministic & identical everywhere), then write
//          ratio / importance / vectorized mask for their 256-pair chunk(s).
__global__ __launch_bounds__(256, 8)
void k_fused(const float* __restrict__ in,
             float* __restrict__ resized,
             float* __restrict__ pmin,
             float* __restrict__ pmax,
             double* __restrict__ psum,
             float* __restrict__ out,
             int npair, int tpp, int num_tokens) {
    const int t    = threadIdx.x;
    const int wid  = t >> 6;
    const int lane = t & 63;
    const int row  = lane >> 2;
    const int c4   = lane & 3;
    const int ngroups = (npair + 3) / 4;

    // ---------------- phase 1 ----------------
    float  mn = INFINITY, mx = -INFINITY;
    double sm = 0.0;

    for (int g = blockIdx.x; g < ngroups; g += gridDim.x) {
        int p = g * 4 + wid;
        if (p < npair) {
            int b   = p / HW2;
            int rem = p - b * HW2;
            int py  = rem / 14;
            int px  = rem - py * 14;
            const float4* src = (const float4*)(in + (size_t)b * IMG2
                                                  + (size_t)(py * 16 + row) * IMG
                                                  + px * 16) + c4;
            float4 v = *src;
            // f32 in-patch reduce (error ~1e-5 << 2e-2 threshold); f64 only
            // for the cross-patch running sum.
            float s = (v.x + v.y) + (v.z + v.w);
            #pragma unroll
            for (int off = 32; off; off >>= 1) s += __shfl_xor(s, off, 64);
            if (lane == 0) {
                float mean = s * (1.0f / 256.0f);
                resized[p] = mean;
                mn = fminf(mn, mean);
                mx = fmaxf(mx, mean);
                sm += (double)mean;
            }
        }
    }

    __shared__ float  smn[4], smx[4];
    __shared__ double ssm[4];
    if (lane == 0) { smn[wid] = mn; smx[wid] = mx; ssm[wid] = sm; }
    __syncthreads();
    if (t == 0) {
        pmin[blockIdx.x] = fminf(fminf(smn[0], smn[1]), fminf(smn[2], smn[3]));
        pmax[blockIdx.x] = fmaxf(fmaxf(smx[0], smx[1]), fmaxf(smx[2], smx[3]));
        psum[blockIdx.x] = ssm[0] + ssm[1] + ssm[2] + ssm[3];
    }

    cg::this_grid().sync();

    // ---------------- phase 2 ----------------
    const int nchunks = (npair + 255) / 256;
    if (blockIdx.x >= nchunks) return;   // idle blocks exit after the sync

    // redundant scalar reduce of gridDim.x partials (L2-resident, fixed order)
    float  rmn = INFINITY, rmx = -INFINITY;
    double rs  = 0.0;
    for (int i = t; i < gridDim.x; i += 256) {
        rmn = fminf(rmn, pmin[i]);
        rmx = fmaxf(rmx, pmax[i]);
        rs += psum[i];
    }
    #pragma unroll
    for (int off = 32; off; off >>= 1) {
        rmn = fminf(rmn, __shfl_xor(rmn, off, 64));
        rmx = fmaxf(rmx, __shfl_xor(rmx, off, 64));
        rs += __shfl_xor(rs, off, 64);
    }
    __shared__ float sc3[3];
    if (lane == 0) { smn[wid] = rmn; smx[wid] = rmx; ssm[wid] = rs; }
    __syncthreads();
    if (t == 0) {
        rmn = fminf(fminf(smn[0], smn[1]), fminf(smn[2], smn[3]));
        rmx = fmaxf(fmaxf(smx[0], smx[1]), fmaxf(smx[2], smx[3]));
        rs  = ssm[0] + ssm[1] + ssm[2] + ssm[3];
        // reference f32 semantics: denom = (m_max - m_min) + 1e-6 in f32
        float denom = __fadd_rn(__fsub_rn(rmx, rmn), 1e-6f);
        double mean     = rs / (double)npair;
        double avg_norm = (mean - (double)rmn) / (double)denom;
        double cur_avg  = 0.25 + 0.75 * avg_norm;          // mean of compression_ratio
        sc3[0] = rmn;
        sc3[1] = denom;
        sc3[2] = (float)(0.5 / (cur_avg + 1e-6));
    }
    __syncthreads();
    const float fmn = sc3[0], fden = sc3[1], fscale = sc3[2];

    __shared__ int      kk[256];
    __shared__ unsigned kbase[256];   // element offset of this pair's mask row
    float* mask = out + 2 * (size_t)npair;

    for (int c = blockIdx.x; c < nchunks; c += gridDim.x) {
        int base = c * 256;
        int g = base + t;
        int k = 0;
        unsigned kb = 0;
        if (g < npair) {
            float r = resized[g];
            // emulate np elementwise f32 rounding: no fma contraction
            float norm   = __fdiv_rn(__fsub_rn(r, fmn), fden);
            float ratio0 = __fadd_rn(0.25f, __fmul_rn(0.75f, norm));
            float sc     = __fmul_rn(ratio0, fscale);
            float ratio  = fminf(fmaxf(sc, 0.25f), 1.0f);
            k = (int)rintf(__fmul_rn(ratio, (float)tpp));   // jnp.round = half-to-even
            k = min(max(k, 1), tpp);
            out[g]         = ratio;   // compression_ratio
            out[npair + g] = norm;    // importance_scores
            unsigned b = (unsigned)g / HW2;
            unsigned p = (unsigned)g - b * HW2;
            kb = b * (unsigned)num_tokens + p * (unsigned)tpp;
        }
        kk[t]    = k;
        kbase[t] = kb;
        __syncthreads();

        int nprs = min(256, npair - base);
        if ((tpp & 3) == 0) {
            int tq = tpp >> 2;
            int total4 = nprs * tq;
            for (int i = t; i < total4; i += 256) {
                int pr = (unsigned)i / (unsigned)tq;
                int wi = (i - pr * tq) * 4;
                int kv = kk[pr];
                float4 m;
                m.x = (wi     < kv) ? 1.0f : 0.0f;
                m.y = (wi + 1 < kv) ? 1.0f : 0.0f;
                m.z = (wi + 2 < kv) ? 1.0f : 0.0f;
                m.w = (wi + 3 < kv) ? 1.0f : 0.0f;
                *(float4*)(mask + (size_t)kbase[pr] + wi) = m;
            }
        } else {
            int total = nprs * tpp;
            for (int i = t; i < total; i += 256) {
                int pr = (unsigned)i / (unsigned)tpp;
                int wi = i - pr * tpp;
                mask[(size_t)kbase[pr] + wi] = (wi < kk[pr]) ? 1.0f : 0.0f;
            }
        }
        __syncthreads();   // before kk/kbase reuse
    }
}

// ---------------- pad (only if 196*tpp < num_tokens; not hit at these sizes) ----
__global__ void k_pad(float* __restrict__ mask, int B, int num_tokens, int used) {
    int per = num_tokens - used;
    int idx = blockIdx.x * 256 + threadIdx.x;
    int tot = B * per;
    if (idx < tot) {
        int b = idx / per;
        int j = idx - b * per;
        mask[(size_t)b * num_tokens + used + j] = 0.0f;
    }
}

extern "C" void kernel_launch(void* const* d_in, const int* in_sizes, int n_in,
                              void* d_out, int out_size, void* d_ws, size_t ws_size,
                              hipStream_t stream) {
    const float* motion = (const float*)d_in[0];
    int nelem = in_sizes[0];                 // B*1*224*224
    int B     = nelem / IMG2;                // 512
    int npair = B * HW2;                     // 100352
    int num_tokens = (out_size - 2 * npair) / B;   // 6272
    int tpp   = num_tokens / HW2;            // 32

    // workspace layout
    float* resized = (float*)d_ws;
    size_t off = ((size_t)npair * sizeof(float) + 7) & ~(size_t)7;
    double* psum = (double*)((char*)d_ws + off);
    float*  pmin = (float*)(psum + MAXBLK);
    float*  pmax = pmin + MAXBLK;
    float*  outp = (float*)d_out;

    // co-residency-safe grid size (required for grid.sync)
    int maxPerCU = 0;
    hipError_t e = hipOccupancyMaxActiveBlocksPerMultiprocessor(&maxPerCU,
                                                                k_fused, 256, 0);
    if (e != hipSuccess || maxPerCU <= 0) maxPerCU = 4;
    int cus = 256;
    e = hipDeviceGetAttribute(&cus, hipDeviceAttributeMultiprocessorCount, 0);
    if (e != hipSuccess || cus <= 0) cus = 256;
    int ngroups = (npair + 3) / 4;
    int grid = cus * maxPerCU;
    if (grid > ngroups) grid = ngroups;
    if (grid > MAXBLK)  grid = MAXBLK;

    void* args[] = { (void*)&motion, (void*)&resized, (void*)&pmin, (void*)&pmax,
                     (void*)&psum, (void*)&outp, (void*)&npair, (void*)&tpp,
                     (void*)&num_tokens };
    e = hipLaunchCooperativeKernel((const void*)k_fused, dim3(grid), dim3(256),
                                   args, 0, stream);
    (void)e;

    int used = HW2 * tpp;
    if (used < num_tokens) {
        int tot = B * (num_tokens - used);
        hipLaunchKernelGGL(k_pad, dim3((tot + 255) / 256), dim3(256), 0, stream,
                           outp + 2 * (size_t)npair, B, num_tokens, used);
    }
}

// Round 6
// 33.303 us; speedup vs baseline: 4.0513x; 4.0513x over previous
//
#include <hip/hip_runtime.h>
#include <math.h>

#define HW2   196      // 14*14
#define IMG   224
#define IMG2  (224*224)
#define PPW   8        // patches per wave (unroll: 8 loads in flight)
#define PPB   32       // patches per block (4 waves)

// ---------------- K1: 16x16 patch means -> resized[B*196], + block partials ----
// Block = 4 waves, 32 consecutive patches. Each wave owns 8 patches:
// issues 8 independent float4 loads (8KB in flight), then 8 shuffle-reduce
// chains advanced in lockstep (independent ds ops -> ILP hides ds latency).
__global__ __launch_bounds__(256) void k_patch_mean(const float* __restrict__ in,
                                                    float* __restrict__ resized,
                                                    float* __restrict__ pmin,
                                                    float* __restrict__ pmax,
                                                    double* __restrict__ psum,
                                                    int npair) {
    const int t    = threadIdx.x;
    const int wid  = t >> 6;
    const int lane = t & 63;
    const int row  = lane >> 2;
    const int c4   = lane & 3;
    const int p0   = blockIdx.x * PPB + wid * PPW;

    float s[PPW];
    #pragma unroll
    for (int k = 0; k < PPW; ++k) {
        int p = p0 + k;
        float4 v = make_float4(0.f, 0.f, 0.f, 0.f);
        if (p < npair) {
            int b   = p / HW2;
            int rem = p - b * HW2;
            int py  = rem / 14;
            int px  = rem - py * 14;
            const float4* src = (const float4*)(in + (size_t)b * IMG2
                                                  + (size_t)(py * 16 + row) * IMG
                                                  + px * 16) + c4;
            v = *src;           // 8 independent loads issued before any reduce
        }
        s[k] = (v.x + v.y) + (v.z + v.w);
    }

    // 8 independent butterfly chains, advanced in lockstep
    #pragma unroll
    for (int off = 32; off; off >>= 1) {
        #pragma unroll
        for (int k = 0; k < PPW; ++k) s[k] += __shfl_xor(s[k], off, 64);
    }

    float  mn = INFINITY, mx = -INFINITY;
    double sm = 0.0;
    if (lane == 0) {
        float m[PPW];
        #pragma unroll
        for (int k = 0; k < PPW; ++k) m[k] = s[k] * (1.0f / 256.0f);
        if (p0 + PPW <= npair) {   // vectorized store (p0 is 8-float aligned)
            *(float4*)(resized + p0)     = make_float4(m[0], m[1], m[2], m[3]);
            *(float4*)(resized + p0 + 4) = make_float4(m[4], m[5], m[6], m[7]);
            #pragma unroll
            for (int k = 0; k < PPW; ++k) {
                mn = fminf(mn, m[k]);
                mx = fmaxf(mx, m[k]);
                sm += (double)m[k];
            }
        } else {
            for (int k = 0; k < PPW && p0 + k < npair; ++k) {
                resized[p0 + k] = m[k];
                mn = fminf(mn, m[k]);
                mx = fmaxf(mx, m[k]);
                sm += (double)m[k];
            }
        }
    }

    __shared__ float  smn[4], smx[4];
    __shared__ double ssm[4];
    if (lane == 0) { smn[wid] = mn; smx[wid] = mx; ssm[wid] = sm; }
    __syncthreads();
    if (t == 0) {
        pmin[blockIdx.x] = fminf(fminf(smn[0], smn[1]), fminf(smn[2], smn[3]));
        pmax[blockIdx.x] = fmaxf(fmaxf(smx[0], smx[1]), fmaxf(smx[2], smx[3]));
        psum[blockIdx.x] = ssm[0] + ssm[1] + ssm[2] + ssm[3];
    }
}

// ---------------- K2: redundant scalar reduce + ratio / importance / mask -------
__global__ __launch_bounds__(256) void k_output(const float* __restrict__ resized,
                                                const float* __restrict__ pmin,
                                                const float* __restrict__ pmax,
                                                const double* __restrict__ psum,
                                                int nblk1,
                                                float* __restrict__ out,
                                                int npair, int tpp, int num_tokens) {
    // redundant reduction of partials (fixed order -> deterministic & identical
    // in every block; partials are L2/L3-resident)
    int t = threadIdx.x;
    float  mn = INFINITY, mx = -INFINITY;
    double s  = 0.0;
    for (int i = t; i < nblk1; i += 256) {
        mn = fminf(mn, pmin[i]);
        mx = fmaxf(mx, pmax[i]);
        s += psum[i];
    }
    #pragma unroll
    for (int off = 32; off; off >>= 1) {
        mn = fminf(mn, __shfl_xor(mn, off, 64));
        mx = fmaxf(mx, __shfl_xor(mx, off, 64));
        s += __shfl_xor(s, off, 64);
    }
    __shared__ float  smn[4], smx[4];
    __shared__ double ssm[4];
    __shared__ float  sc3[3];
    int wid = t >> 6, lane = t & 63;
    if (lane == 0) { smn[wid] = mn; smx[wid] = mx; ssm[wid] = s; }
    __syncthreads();
    if (t == 0) {
        mn = fminf(fminf(smn[0], smn[1]), fminf(smn[2], smn[3]));
        mx = fmaxf(fmaxf(smx[0], smx[1]), fmaxf(smx[2], smx[3]));
        s  = ssm[0] + ssm[1] + ssm[2] + ssm[3];
        // reference f32 semantics: denom = (m_max - m_min) + 1e-6 in f32
        float denom = __fadd_rn(__fsub_rn(mx, mn), 1e-6f);
        double mean     = s / (double)npair;
        double avg_norm = (mean - (double)mn) / (double)denom;
        double cur_avg  = 0.25 + 0.75 * avg_norm;          // mean of compression_ratio
        sc3[0] = mn;
        sc3[1] = denom;
        sc3[2] = (float)(0.5 / (cur_avg + 1e-6));
    }
    __syncthreads();
    const float fmn = sc3[0], fden = sc3[1], fscale = sc3[2];

    // per-pair outputs
    int base = blockIdx.x * 256;
    int g = base + t;
    __shared__ int      kk[256];
    __shared__ unsigned kbase[256];   // element offset of this pair's mask row
    int k = 0;
    unsigned kb = 0;
    if (g < npair) {
        float r = resized[g];
        // emulate np elementwise f32 rounding: no fma contraction
        float norm   = __fdiv_rn(__fsub_rn(r, fmn), fden);
        float ratio0 = __fadd_rn(0.25f, __fmul_rn(0.75f, norm));
        float sc     = __fmul_rn(ratio0, fscale);
        float ratio  = fminf(fmaxf(sc, 0.25f), 1.0f);
        k = (int)rintf(__fmul_rn(ratio, (float)tpp));   // jnp.round = half-to-even
        k = min(max(k, 1), tpp);
        out[g]         = ratio;   // compression_ratio
        out[npair + g] = norm;    // importance_scores
        unsigned b = (unsigned)g / HW2;
        unsigned p = (unsigned)g - b * HW2;
        kb = b * (unsigned)num_tokens + p * (unsigned)tpp;
    }
    kk[t]    = k;
    kbase[t] = kb;
    __syncthreads();

    float* mask = out + 2 * (size_t)npair;
    int nprs = min(256, npair - base);
    if ((tpp & 3) == 0) {
        int tq = tpp >> 2;
        int total4 = nprs * tq;
        for (int i = t; i < total4; i += 256) {
            int pr = (unsigned)i / (unsigned)tq;
            int wi = (i - pr * tq) * 4;
            int kv = kk[pr];
            float4 m;
            m.x = (wi     < kv) ? 1.0f : 0.0f;
            m.y = (wi + 1 < kv) ? 1.0f : 0.0f;
            m.z = (wi + 2 < kv) ? 1.0f : 0.0f;
            m.w = (wi + 3 < kv) ? 1.0f : 0.0f;
            *(float4*)(mask + (size_t)kbase[pr] + wi) = m;
        }
    } else {
        int total = nprs * tpp;
        for (int i = t; i < total; i += 256) {
            int pr = (unsigned)i / (unsigned)tpp;
            int wi = i - pr * tpp;
            mask[(size_t)kbase[pr] + wi] = (wi < kk[pr]) ? 1.0f : 0.0f;
        }
    }
}

// ---------------- pad (only if 196*tpp < num_tokens; not hit at these sizes) ----
__global__ void k_pad(float* __restrict__ mask, int B, int num_tokens, int used) {
    int per = num_tokens - used;
    int idx = blockIdx.x * 256 + threadIdx.x;
    int tot = B * per;
    if (idx < tot) {
        int b = idx / per;
        int j = idx - b * per;
        mask[(size_t)b * num_tokens + used + j] = 0.0f;
    }
}

extern "C" void kernel_launch(void* const* d_in, const int* in_sizes, int n_in,
                              void* d_out, int out_size, void* d_ws, size_t ws_size,
                              hipStream_t stream) {
    const float* motion = (const float*)d_in[0];
    int nelem = in_sizes[0];                 // B*1*224*224
    int B     = nelem / IMG2;                // 512
    int npair = B * HW2;                     // 100352
    int num_tokens = (out_size - 2 * npair) / B;   // 6272
    int tpp   = num_tokens / HW2;            // 32

    int nb1 = (npair + PPB - 1) / PPB;       // 3136

    // workspace layout
    float* resized = (float*)d_ws;
    size_t off = ((size_t)npair * sizeof(float) + 7) & ~(size_t)7;
    double* psum = (double*)((char*)d_ws + off);
    float*  pmin = (float*)(psum + nb1);
    float*  pmax = pmin + nb1;

    hipLaunchKernelGGL(k_patch_mean, dim3(nb1), dim3(256), 0, stream,
                       motion, resized, pmin, pmax, psum, npair);

    int nb2 = (npair + 255) / 256;           // 392
    hipLaunchKernelGGL(k_output, dim3(nb2), dim3(256), 0, stream,
                       resized, pmin, pmax, psum, nb1,
                       (float*)d_out, npair, tpp, num_tokens);

    int used = HW2 * tpp;
    if (used < num_tokens) {
        int tot = B * (num_tokens - used);
        hipLaunchKernelGGL(k_pad, dim3((tot + 255) / 256), dim3(256), 0, stream,
                           (float*)d_out + 2 * (size_t)npair, B, num_tokens, used);
    }
}

// Round 7
// 30.451 us; speedup vs baseline: 4.4308x; 1.0937x over previous
//
#include <hip/hip_runtime.h>
#include <math.h>

#define HW2   196      // 14*14
#define IMG   224
#define IMG2  (224*224)
#define SPB   4        // strips per block (4 waves)
#define NIT   14       // 3584 floats / 256 per wave-iteration

// ---------------- K1: strip-contiguous patch means ----------------
// Strip = one patch-row of one image = contiguous 16*224 floats.
// One wave per strip: 14 iterations of lane-contiguous float4 (1KB/instr,
// perfectly coalesced). 4-lane shuffle reduce -> LDS atomicAdd into per-wave
// patch sums (patch of group g at iter it = (g + 2*it) % 14).
__global__ __launch_bounds__(256) void k_patch_mean(const float* __restrict__ in,
                                                    float* __restrict__ resized,
                                                    float* __restrict__ pmin,
                                                    float* __restrict__ pmax,
                                                    double* __restrict__ psum,
                                                    int nstrips) {
    const int t    = threadIdx.x;
    const int wid  = t >> 6;
    const int lane = t & 63;
    const int s    = blockIdx.x * SPB + wid;

    __shared__ float  sums[SPB][14];
    __shared__ float  smn[SPB], smx[SPB];
    __shared__ double ssm[SPB];

    if (lane < 14) sums[wid][lane] = 0.0f;
    // per-wave LDS ops complete in order; no cross-wave use of sums -> no sync needed

    if (s < nstrips) {
        const float4* strip = (const float4*)(in + (size_t)s * (16 * IMG));
        #pragma unroll
        for (int it = 0; it < NIT; ++it) {
            float4 v = strip[it * 64 + lane];
            float x = (v.x + v.y) + (v.z + v.w);
            x += __shfl_xor(x, 1, 64);
            x += __shfl_xor(x, 2, 64);
            if ((lane & 3) == 0) {
                int p = (lane >> 2) + 2 * it;   // < 42
                if (p >= 28) p -= 28; else if (p >= 14) p -= 14;
                atomicAdd(&sums[wid][p], x);
            }
        }
    }

    // wave-level: read own sums (in-order LDS guarantees atomics done)
    float  mnv = INFINITY, mxv = -INFINITY;
    double sv  = 0.0;
    if (s < nstrips && lane < 14) {
        float mean = sums[wid][lane] * (1.0f / 256.0f);
        resized[s * 14 + lane] = mean;
        mnv = mean; mxv = mean; sv = (double)mean;
    }
    #pragma unroll
    for (int off = 32; off; off >>= 1) {
        mnv = fminf(mnv, __shfl_xor(mnv, off, 64));
        mxv = fmaxf(mxv, __shfl_xor(mxv, off, 64));
        sv += __shfl_xor(sv, off, 64);
    }
    if (lane == 0) { smn[wid] = mnv; smx[wid] = mxv; ssm[wid] = sv; }
    __syncthreads();
    if (t == 0) {
        pmin[blockIdx.x] = fminf(fminf(smn[0], smn[1]), fminf(smn[2], smn[3]));
        pmax[blockIdx.x] = fmaxf(fmaxf(smx[0], smx[1]), fmaxf(smx[2], smx[3]));
        psum[blockIdx.x] = ssm[0] + ssm[1] + ssm[2] + ssm[3];
    }
}

// ---------------- K2: redundant scalar reduce + ratio / importance / mask -------
__global__ __launch_bounds__(256) void k_output(const float* __restrict__ resized,
                                                const float* __restrict__ pmin,
                                                const float* __restrict__ pmax,
                                                const double* __restrict__ psum,
                                                int nblk1,
                                                float* __restrict__ out,
                                                int npair, int tpp, int num_tokens) {
    // redundant reduction of partials (fixed order -> deterministic & identical
    // in every block; partials are L2/L3-resident)
    int t = threadIdx.x;
    float  mn = INFINITY, mx = -INFINITY;
    double s  = 0.0;
    for (int i = t; i < nblk1; i += 256) {
        mn = fminf(mn, pmin[i]);
        mx = fmaxf(mx, pmax[i]);
        s += psum[i];
    }
    #pragma unroll
    for (int off = 32; off; off >>= 1) {
        mn = fminf(mn, __shfl_xor(mn, off, 64));
        mx = fmaxf(mx, __shfl_xor(mx, off, 64));
        s += __shfl_xor(s, off, 64);
    }
    __shared__ float  smn[4], smx[4];
    __shared__ double ssm[4];
    __shared__ float  sc3[3];
    int wid = t >> 6, lane = t & 63;
    if (lane == 0) { smn[wid] = mn; smx[wid] = mx; ssm[wid] = s; }
    __syncthreads();
    if (t == 0) {
        mn = fminf(fminf(smn[0], smn[1]), fminf(smn[2], smn[3]));
        mx = fmaxf(fmaxf(smx[0], smx[1]), fmaxf(smx[2], smx[3]));
        s  = ssm[0] + ssm[1] + ssm[2] + ssm[3];
        // reference f32 semantics: denom = (m_max - m_min) + 1e-6 in f32
        float denom = __fadd_rn(__fsub_rn(mx, mn), 1e-6f);
        double mean     = s / (double)npair;
        double avg_norm = (mean - (double)mn) / (double)denom;
        double cur_avg  = 0.25 + 0.75 * avg_norm;          // mean of compression_ratio
        sc3[0] = mn;
        sc3[1] = denom;
        sc3[2] = (float)(0.5 / (cur_avg + 1e-6));
    }
    __syncthreads();
    const float fmn = sc3[0], fden = sc3[1], fscale = sc3[2];

    // per-pair outputs
    int base = blockIdx.x * 256;
    int g = base + t;
    __shared__ int      kk[256];
    __shared__ unsigned kbase[256];   // element offset of this pair's mask row
    int k = 0;
    unsigned kb = 0;
    if (g < npair) {
        float r = resized[g];
        // emulate np elementwise f32 rounding: no fma contraction
        float norm   = __fdiv_rn(__fsub_rn(r, fmn), fden);
        float ratio0 = __fadd_rn(0.25f, __fmul_rn(0.75f, norm));
        float sc     = __fmul_rn(ratio0, fscale);
        float ratio  = fminf(fmaxf(sc, 0.25f), 1.0f);
        k = (int)rintf(__fmul_rn(ratio, (float)tpp));   // jnp.round = half-to-even
        k = min(max(k, 1), tpp);
        out[g]         = ratio;   // compression_ratio
        out[npair + g] = norm;    // importance_scores
        unsigned b = (unsigned)g / HW2;
        unsigned p = (unsigned)g - b * HW2;
        kb = b * (unsigned)num_tokens + p * (unsigned)tpp;
    }
    kk[t]    = k;
    kbase[t] = kb;
    __syncthreads();

    float* mask = out + 2 * (size_t)npair;
    int nprs = min(256, npair - base);
    if ((tpp & 3) == 0) {
        int tq = tpp >> 2;
        int total4 = nprs * tq;
        for (int i = t; i < total4; i += 256) {
            int pr = (unsigned)i / (unsigned)tq;
            int wi = (i - pr * tq) * 4;
            int kv = kk[pr];
            float4 m;
            m.x = (wi     < kv) ? 1.0f : 0.0f;
            m.y = (wi + 1 < kv) ? 1.0f : 0.0f;
            m.z = (wi + 2 < kv) ? 1.0f : 0.0f;
            m.w = (wi + 3 < kv) ? 1.0f : 0.0f;
            *(float4*)(mask + (size_t)kbase[pr] + wi) = m;
        }
    } else {
        int total = nprs * tpp;
        for (int i = t; i < total; i += 256) {
            int pr = (unsigned)i / (unsigned)tpp;
            int wi = i - pr * tpp;
            mask[(size_t)kbase[pr] + wi] = (wi < kk[pr]) ? 1.0f : 0.0f;
        }
    }
}

// ---------------- pad (only if 196*tpp < num_tokens; not hit at these sizes) ----
__global__ void k_pad(float* __restrict__ mask, int B, int num_tokens, int used) {
    int per = num_tokens - used;
    int idx = blockIdx.x * 256 + threadIdx.x;
    int tot = B * per;
    if (idx < tot) {
        int b = idx / per;
        int j = idx - b * per;
        mask[(size_t)b * num_tokens + used + j] = 0.0f;
    }
}

extern "C" void kernel_launch(void* const* d_in, const int* in_sizes, int n_in,
                              void* d_out, int out_size, void* d_ws, size_t ws_size,
                              hipStream_t stream) {
    const float* motion = (const float*)d_in[0];
    int nelem = in_sizes[0];                 // B*1*224*224
    int B     = nelem / IMG2;                // 512
    int npair = B * HW2;                     // 100352
    int num_tokens = (out_size - 2 * npair) / B;   // 6272
    int tpp   = num_tokens / HW2;            // 32

    int nstrips = npair / 14;                // 7168 (one strip = 14 patches)
    int nb1 = (nstrips + SPB - 1) / SPB;     // 1792

    // workspace layout
    float* resized = (float*)d_ws;
    size_t off = ((size_t)npair * sizeof(float) + 7) & ~(size_t)7;
    double* psum = (double*)((char*)d_ws + off);
    float*  pmin = (float*)(psum + nb1);
    float*  pmax = pmin + nb1;

    hipLaunchKernelGGL(k_patch_mean, dim3(nb1), dim3(256), 0, stream,
                       motion, resized, pmin, pmax, psum, nstrips);

    int nb2 = (npair + 255) / 256;           // 392
    hipLaunchKernelGGL(k_output, dim3(nb2), dim3(256), 0, stream,
                       resized, pmin, pmax, psum, nb1,
                       (float*)d_out, npair, tpp, num_tokens);

    int used = HW2 * tpp;
    if (used < num_tokens) {
        int tot = B * (num_tokens - used);
        hipLaunchKernelGGL(k_pad, dim3((tot + 255) / 256), dim3(256), 0, stream,
                           (float*)d_out + 2 * (size_t)npair, B, num_tokens, used);
    }
}

// Round 8
// 28.491 us; speedup vs baseline: 4.7356x; 1.0688x over previous
//
#include <hip/hip_runtime.h>
#include <math.h>

#define HW2   196      // 14*14
#define IMG   224
#define IMG2  (224*224)
#define SPB   4        // strips per block (4 waves, one strip per wave)

// ---------------- K1: strip-contiguous patch means, zero cross-lane in loop ----
// Strip = one patch-row of one image = contiguous 16*224 floats.
// One wave per strip. Lane l<56 owns columns 4l..4l+3: accumulates a private
// float4 over the 16 rows (16 unrolled independent 896B-contiguous loads,
// pure load+fadd). Cross-lane work happens ONCE per strip at the end:
// horizontal add + 2 shuffles -> patch sums at lanes 4p, broadcast-gather to
// lanes 0..13, contiguous 56B store.
__global__ __launch_bounds__(256) void k_patch_mean(const float* __restrict__ in,
                                                    float* __restrict__ resized,
                                                    float* __restrict__ pmin,
                                                    float* __restrict__ pmax,
                                                    double* __restrict__ psum,
                                                    int nstrips) {
    const int t    = threadIdx.x;
    const int wid  = t >> 6;
    const int lane = t & 63;
    const int s    = blockIdx.x * SPB + wid;

    float4 acc = make_float4(0.f, 0.f, 0.f, 0.f);
    if (s < nstrips && lane < 56) {
        const float4* strip = (const float4*)(in + (size_t)s * (16 * IMG)) + lane;
        #pragma unroll
        for (int r = 0; r < 16; ++r) {
            float4 v = strip[r * 56];
            acc.x += v.x; acc.y += v.y; acc.z += v.z; acc.w += v.w;
        }
    }
    // one cross-lane phase per strip
    float h = (acc.x + acc.y) + (acc.z + acc.w);   // lane: sum of its 4 cols
    h += __shfl_xor(h, 1, 64);
    h += __shfl_xor(h, 2, 64);                     // lane 4p holds patch sum p
    float g = __shfl(h, lane * 4, 64);             // lane p<14 gathers patch p

    float  mnv = INFINITY, mxv = -INFINITY;
    double sv  = 0.0;
    if (s < nstrips && lane < 14) {
        float mean = g * (1.0f / 256.0f);
        resized[s * 14 + lane] = mean;             // contiguous 56B per wave
        mnv = mean; mxv = mean; sv = (double)mean;
    }
    #pragma unroll
    for (int off = 32; off; off >>= 1) {
        mnv = fminf(mnv, __shfl_xor(mnv, off, 64));
        mxv = fmaxf(mxv, __shfl_xor(mxv, off, 64));
        sv += __shfl_xor(sv, off, 64);
    }
    __shared__ float  smn[SPB], smx[SPB];
    __shared__ double ssm[SPB];
    if (lane == 0) { smn[wid] = mnv; smx[wid] = mxv; ssm[wid] = sv; }
    __syncthreads();
    if (t == 0) {
        pmin[blockIdx.x] = fminf(fminf(smn[0], smn[1]), fminf(smn[2], smn[3]));
        pmax[blockIdx.x] = fmaxf(fmaxf(smx[0], smx[1]), fmaxf(smx[2], smx[3]));
        psum[blockIdx.x] = ssm[0] + ssm[1] + ssm[2] + ssm[3];
    }
}

// ---------------- K2: redundant scalar reduce + ratio / importance / mask -------
__global__ __launch_bounds__(256) void k_output(const float* __restrict__ resized,
                                                const float* __restrict__ pmin,
                                                const float* __restrict__ pmax,
                                                const double* __restrict__ psum,
                                                int nblk1,
                                                float* __restrict__ out,
                                                int npair, int tpp, int num_tokens) {
    // redundant reduction of partials (fixed order -> deterministic & identical
    // in every block; partials are L2/L3-resident)
    int t = threadIdx.x;
    float  mn = INFINITY, mx = -INFINITY;
    double s  = 0.0;
    for (int i = t; i < nblk1; i += 256) {
        mn = fminf(mn, pmin[i]);
        mx = fmaxf(mx, pmax[i]);
        s += psum[i];
    }
    #pragma unroll
    for (int off = 32; off; off >>= 1) {
        mn = fminf(mn, __shfl_xor(mn, off, 64));
        mx = fmaxf(mx, __shfl_xor(mx, off, 64));
        s += __shfl_xor(s, off, 64);
    }
    __shared__ float  smn[4], smx[4];
    __shared__ double ssm[4];
    __shared__ float  sc3[3];
    int wid = t >> 6, lane = t & 63;
    if (lane == 0) { smn[wid] = mn; smx[wid] = mx; ssm[wid] = s; }
    __syncthreads();
    if (t == 0) {
        mn = fminf(fminf(smn[0], smn[1]), fminf(smn[2], smn[3]));
        mx = fmaxf(fmaxf(smx[0], smx[1]), fmaxf(smx[2], smx[3]));
        s  = ssm[0] + ssm[1] + ssm[2] + ssm[3];
        // reference f32 semantics: denom = (m_max - m_min) + 1e-6 in f32
        float denom = __fadd_rn(__fsub_rn(mx, mn), 1e-6f);
        double mean     = s / (double)npair;
        double avg_norm = (mean - (double)mn) / (double)denom;
        double cur_avg  = 0.25 + 0.75 * avg_norm;          // mean of compression_ratio
        sc3[0] = mn;
        sc3[1] = denom;
        sc3[2] = (float)(0.5 / (cur_avg + 1e-6));
    }
    __syncthreads();
    const float fmn = sc3[0], fden = sc3[1], fscale = sc3[2];

    // per-pair outputs
    int base = blockIdx.x * 256;
    int g = base + t;
    __shared__ int      kk[256];
    __shared__ unsigned kbase[256];   // element offset of this pair's mask row
    int k = 0;
    unsigned kb = 0;
    if (g < npair) {
        float r = resized[g];
        // emulate np elementwise f32 rounding: no fma contraction
        float norm   = __fdiv_rn(__fsub_rn(r, fmn), fden);
        float ratio0 = __fadd_rn(0.25f, __fmul_rn(0.75f, norm));
        float sc     = __fmul_rn(ratio0, fscale);
        float ratio  = fminf(fmaxf(sc, 0.25f), 1.0f);
        k = (int)rintf(__fmul_rn(ratio, (float)tpp));   // jnp.round = half-to-even
        k = min(max(k, 1), tpp);
        out[g]         = ratio;   // compression_ratio
        out[npair + g] = norm;    // importance_scores
        unsigned b = (unsigned)g / HW2;
        unsigned p = (unsigned)g - b * HW2;
        kb = b * (unsigned)num_tokens + p * (unsigned)tpp;
    }
    kk[t]    = k;
    kbase[t] = kb;
    __syncthreads();

    float* mask = out + 2 * (size_t)npair;
    int nprs = min(256, npair - base);
    if ((tpp & 3) == 0) {
        int tq = tpp >> 2;
        int total4 = nprs * tq;
        for (int i = t; i < total4; i += 256) {
            int pr = (unsigned)i / (unsigned)tq;
            int wi = (i - pr * tq) * 4;
            int kv = kk[pr];
            float4 m;
            m.x = (wi     < kv) ? 1.0f : 0.0f;
            m.y = (wi + 1 < kv) ? 1.0f : 0.0f;
            m.z = (wi + 2 < kv) ? 1.0f : 0.0f;
            m.w = (wi + 3 < kv) ? 1.0f : 0.0f;
            *(float4*)(mask + (size_t)kbase[pr] + wi) = m;
        }
    } else {
        int total = nprs * tpp;
        for (int i = t; i < total; i += 256) {
            int pr = (unsigned)i / (unsigned)tpp;
            int wi = i - pr * tpp;
            mask[(size_t)kbase[pr] + wi] = (wi < kk[pr]) ? 1.0f : 0.0f;
        }
    }
}

// ---------------- pad (only if 196*tpp < num_tokens; not hit at these sizes) ----
__global__ void k_pad(float* __restrict__ mask, int B, int num_tokens, int used) {
    int per = num_tokens - used;
    int idx = blockIdx.x * 256 + threadIdx.x;
    int tot = B * per;
    if (idx < tot) {
        int b = idx / per;
        int j = idx - b * per;
        mask[(size_t)b * num_tokens + used + j] = 0.0f;
    }
}

extern "C" void kernel_launch(void* const* d_in, const int* in_sizes, int n_in,
                              void* d_out, int out_size, void* d_ws, size_t ws_size,
                              hipStream_t stream) {
    const float* motion = (const float*)d_in[0];
    int nelem = in_sizes[0];                 // B*1*224*224
    int B     = nelem / IMG2;                // 512
    int npair = B * HW2;                     // 100352
    int num_tokens = (out_size - 2 * npair) / B;   // 6272
    int tpp   = num_tokens / HW2;            // 32

    int nstrips = npair / 14;                // 7168 (one strip = 14 patches)
    int nb1 = (nstrips + SPB - 1) / SPB;     // 1792

    // workspace layout
    float* resized = (float*)d_ws;
    size_t off = ((size_t)npair * sizeof(float) + 7) & ~(size_t)7;
    double* psum = (double*)((char*)d_ws + off);
    float*  pmin = (float*)(psum + nb1);
    float*  pmax = pmin + nb1;

    hipLaunchKernelGGL(k_patch_mean, dim3(nb1), dim3(256), 0, stream,
                       motion, resized, pmin, pmax, psum, nstrips);

    int nb2 = (npair + 255) / 256;           // 392
    hipLaunchKernelGGL(k_output, dim3(nb2), dim3(256), 0, stream,
                       resized, pmin, pmax, psum, nb1,
                       (float*)d_out, npair, tpp, num_tokens);

    int used = HW2 * tpp;
    if (used < num_tokens) {
        int tot = B * (num_tokens - used);
        hipLaunchKernelGGL(k_pad, dim3((tot + 255) / 256), dim3(256), 0, stream,
                           (float*)d_out + 2 * (size_t)npair, B, num_tokens, used);
    }
}

// Round 10
// 28.218 us; speedup vs baseline: 4.7815x; 1.0097x over previous
//
#include <hip/hip_runtime.h>
#include <math.h>

#define HW2   196      // 14*14
#define IMG   224
#define IMG2  (224*224)
#define SPB   4        // strips per block (4 waves, one strip per wave)

typedef float f32x4 __attribute__((ext_vector_type(4)));

// ---------------- K1: strip-contiguous patch means, minimal reduce tail ----
// Strip = one patch-row of one image = contiguous 16*224 floats.
// One wave per strip. Lane l<56 owns columns 4l..4l+3: accumulates a private
// float4 over the 16 rows (16 unrolled independent 896B nt-loads, pure
// load+fadd). Tail: 3 shuffles -> 14 patch means -> LDS; wave 0 alone does
// one 56-wide f32 butterfly for the block's {min,max,sum} partials.
__global__ __launch_bounds__(256) void k_patch_mean(const float* __restrict__ in,
                                                    float* __restrict__ resized,
                                                    float* __restrict__ pmin,
                                                    float* __restrict__ pmax,
                                                    float* __restrict__ psum,
                                                    int nstrips) {
    const int t    = threadIdx.x;
    const int wid  = t >> 6;
    const int lane = t & 63;
    const int s    = blockIdx.x * SPB + wid;

    f32x4 acc = (f32x4)(0.f);
    if (s < nstrips && lane < 56) {
        const f32x4* strip = (const f32x4*)(in + (size_t)s * (16 * IMG)) + lane;
        #pragma unroll
        for (int r = 0; r < 16; ++r) {
            f32x4 v = __builtin_nontemporal_load(&strip[r * 56]);
            acc += v;
        }
    }
    // once-per-strip cross-lane: column sums -> patch sums at lanes 4p
    float h = (acc.x + acc.y) + (acc.z + acc.w);
    h += __shfl_xor(h, 1, 64);
    h += __shfl_xor(h, 2, 64);
    float g = __shfl(h, lane * 4, 64);             // lane p<14 gathers patch p

    __shared__ float means[SPB * 14];
    if (s < nstrips && lane < 14) {
        float mean = g * (1.0f / 256.0f);
        resized[s * 14 + lane] = mean;             // contiguous 56B per wave
        means[wid * 14 + lane] = mean;
    }
    __syncthreads();

    if (wid == 0) {                                // wave 0 reduces the block
        float mnv = INFINITY, mxv = -INFINITY, sv = 0.0f;
        if (lane < SPB * 14) {
            int s2 = blockIdx.x * SPB + (lane / 14);
            if (s2 < nstrips) {
                float m = means[lane];
                mnv = m; mxv = m; sv = m;
            }
        }
        #pragma unroll
        for (int off = 32; off; off >>= 1) {
            mnv = fminf(mnv, __shfl_xor(mnv, off, 64));
            mxv = fmaxf(mxv, __shfl_xor(mxv, off, 64));
            sv += __shfl_xor(sv, off, 64);
        }
        if (lane == 0) {
            pmin[blockIdx.x] = mnv;
            pmax[blockIdx.x] = mxv;
            psum[blockIdx.x] = sv;   // f32 block partial (56 values, exact order)
        }
    }
}

// ---------------- K1b: single block reduces partials -> {m_min, denom, scale} --
__global__ __launch_bounds__(256) void k_scalars(const float* __restrict__ pmin,
                                                 const float* __restrict__ pmax,
                                                 const float* __restrict__ psum,
                                                 int nblk1, int npair,
                                                 float* __restrict__ sc3) {
    int t = threadIdx.x;
    float  mn = INFINITY, mx = -INFINITY;
    double s  = 0.0;
    for (int i = t; i < nblk1; i += 256) {
        mn = fminf(mn, pmin[i]);
        mx = fmaxf(mx, pmax[i]);
        s += (double)psum[i];
    }
    #pragma unroll
    for (int off = 32; off; off >>= 1) {
        mn = fminf(mn, __shfl_xor(mn, off, 64));
        mx = fmaxf(mx, __shfl_xor(mx, off, 64));
        s += __shfl_xor(s, off, 64);
    }
    __shared__ float  smn[4], smx[4];
    __shared__ double ssm[4];
    int wid = t >> 6, lane = t & 63;
    if (lane == 0) { smn[wid] = mn; smx[wid] = mx; ssm[wid] = s; }
    __syncthreads();
    if (t == 0) {
        mn = fminf(fminf(smn[0], smn[1]), fminf(smn[2], smn[3]));
        mx = fmaxf(fmaxf(smx[0], smx[1]), fmaxf(smx[2], smx[3]));
        s  = ssm[0] + ssm[1] + ssm[2] + ssm[3];
        // reference f32 semantics: denom = (m_max - m_min) + 1e-6 in f32
        float denom = __fadd_rn(__fsub_rn(mx, mn), 1e-6f);
        double mean     = s / (double)npair;
        double avg_norm = (mean - (double)mn) / (double)denom;
        double cur_avg  = 0.25 + 0.75 * avg_norm;          // mean of compression_ratio
        sc3[0] = mn;
        sc3[1] = denom;
        sc3[2] = (float)(0.5 / (cur_avg + 1e-6));
    }
}

// ---------------- K2: pure stream-out of ratio / importance / mask ----------
__global__ __launch_bounds__(256) void k_output(const float* __restrict__ resized,
                                                const float* __restrict__ sc3,
                                                float* __restrict__ out,
                                                int npair, int tpp, int num_tokens) {
    int t = threadIdx.x;
    const float fmn = sc3[0], fden = sc3[1], fscale = sc3[2];

    int base = blockIdx.x * 256;
    int g = base + t;
    __shared__ int      kk[256];
    __shared__ unsigned kbase[256];   // element offset of this pair's mask row
    int k = 0;
    unsigned kb = 0;
    if (g < npair) {
        float r = resized[g];
        // emulate np elementwise f32 rounding: no fma contraction
        float norm   = __fdiv_rn(__fsub_rn(r, fmn), fden);
        float ratio0 = __fadd_rn(0.25f, __fmul_rn(0.75f, norm));
        float sc     = __fmul_rn(ratio0, fscale);
        float ratio  = fminf(fmaxf(sc, 0.25f), 1.0f);
        k = (int)rintf(__fmul_rn(ratio, (float)tpp));   // jnp.round = half-to-even
        k = min(max(k, 1), tpp);
        out[g]         = ratio;   // compression_ratio
        out[npair + g] = norm;    // importance_scores
        unsigned b = (unsigned)g / HW2;
        unsigned p = (unsigned)g - b * HW2;
        kb = b * (unsigned)num_tokens + p * (unsigned)tpp;
    }
    kk[t]    = k;
    kbase[t] = kb;
    __syncthreads();

    float* mask = out + 2 * (size_t)npair;
    int nprs = min(256, npair - base);
    if ((tpp & 3) == 0) {
        int tq = tpp >> 2;
        int total4 = nprs * tq;
        for (int i = t; i < total4; i += 256) {
            int pr = (unsigned)i / (unsigned)tq;
            int wi = (i - pr * tq) * 4;
            int kv = kk[pr];
            float4 m;
            m.x = (wi     < kv) ? 1.0f : 0.0f;
            m.y = (wi + 1 < kv) ? 1.0f : 0.0f;
            m.z = (wi + 2 < kv) ? 1.0f : 0.0f;
            m.w = (wi + 3 < kv) ? 1.0f : 0.0f;
            *(float4*)(mask + (size_t)kbase[pr] + wi) = m;
        }
    } else {
        int total = nprs * tpp;
        for (int i = t; i < total; i += 256) {
            int pr = (unsigned)i / (unsigned)tpp;
            int wi = i - pr * tpp;
            mask[(size_t)kbase[pr] + wi] = (wi < kk[pr]) ? 1.0f : 0.0f;
        }
    }
}

// ---------------- pad (only if 196*tpp < num_tokens; not hit at these sizes) ----
__global__ void k_pad(float* __restrict__ mask, int B, int num_tokens, int used) {
    int per = num_tokens - used;
    int idx = blockIdx.x * 256 + threadIdx.x;
    int tot = B * per;
    if (idx < tot) {
        int b = idx / per;
        int j = idx - b * per;
        mask[(size_t)b * num_tokens + used + j] = 0.0f;
    }
}

extern "C" void kernel_launch(void* const* d_in, const int* in_sizes, int n_in,
                              void* d_out, int out_size, void* d_ws, size_t ws_size,
                              hipStream_t stream) {
    const float* motion = (const float*)d_in[0];
    int nelem = in_sizes[0];                 // B*1*224*224
    int B     = nelem / IMG2;                // 512
    int npair = B * HW2;                     // 100352
    int num_tokens = (out_size - 2 * npair) / B;   // 6272
    int tpp   = num_tokens / HW2;            // 32

    int nstrips = npair / 14;                // 7168 (one strip = 14 patches)
    int nb1 = (nstrips + SPB - 1) / SPB;     // 1792

    // workspace layout (all f32)
    float* resized = (float*)d_ws;
    float* psum = resized + npair;
    float* pmin = psum + nb1;
    float* pmax = pmin + nb1;
    float* sc3  = pmax + nb1;

    hipLaunchKernelGGL(k_patch_mean, dim3(nb1), dim3(256), 0, stream,
                       motion, resized, pmin, pmax, psum, nstrips);

    hipLaunchKernelGGL(k_scalars, dim3(1), dim3(256), 0, stream,
                       pmin, pmax, psum, nb1, npair, sc3);

    int nb2 = (npair + 255) / 256;           // 392
    hipLaunchKernelGGL(k_output, dim3(nb2), dim3(256), 0, stream,
                       resized, sc3, (float*)d_out, npair, tpp, num_tokens);

    int used = HW2 * tpp;
    if (used < num_tokens) {
        int tot = B * (num_tokens - used);
        hipLaunchKernelGGL(k_pad, dim3((tot + 255) / 256), dim3(256), 0, stream,
                           (float*)d_out + 2 * (size_t)npair, B, num_tokens, used);
    }
}